// Round 4
// baseline (1126.072 us; speedup 1.0000x reference)
//
#include <hip/hip_runtime.h>
#include <hip/hip_bf16.h>

// ---------------------------------------------------------------------------
// GCNRegression: 4x (GEMM 128x128 + symmetric-norm aggregation + ReLU),
// then global mean pool (128 graphs) + FC(128->1).
//
// R3 notes:
//  - agg was 4x106us with FETCH_SIZE=359MB (random 512B row gathers, ~56% L2
//    hit). Fix: channel-blocked h layout [8][N][16]; agg pass = blockIdx&7 so
//    each XCD gathers from a private 3.2MB slice that fits its 4MB L2.
//    csr_src stream loads are nontemporal to protect the hot slice.
//  - gemm: 64-row tiles (1564 blocks, ~6/CU) for latency hiding; reads
//    standard layout (layer 1) or blocked (layers 2-4); writes blocked.
// ---------------------------------------------------------------------------

// ---- degree histogram (int4-vectorized edge reads) ------------------------
__global__ void count_deg_kernel(const int* __restrict__ dst, int* __restrict__ deg, int E) {
    int i = blockIdx.x * blockDim.x + threadIdx.x;
    int e = i * 4;
    if (e + 3 < E) {
        int4 d = *(const int4*)(dst + e);
        atomicAdd(&deg[d.x], 1);
        atomicAdd(&deg[d.y], 1);
        atomicAdd(&deg[d.z], 1);
        atomicAdd(&deg[d.w], 1);
    } else {
        for (; e < E; e++) atomicAdd(&deg[dst[e]], 1);
    }
}

// ---- dinv = 1/sqrt(deg+1) -------------------------------------------------
__global__ void dinv_kernel(const int* __restrict__ deg, float* __restrict__ dinv, int n) {
    int i = blockIdx.x * blockDim.x + threadIdx.x;
    if (i < n) dinv[i] = (float)(1.0 / sqrt((double)(deg[i] + 1)));
}

// ---- single-block exclusive scan -> row_ptr -------------------------------
__global__ void scan_kernel(const int* __restrict__ cnt, int* __restrict__ row_ptr, int n) {
    __shared__ int sums[1024];
    int t = threadIdx.x;
    int per = (n + 1023) >> 10;
    int s = t * per;
    int e = s + per; if (e > n) e = n; if (s > n) s = n;
    int acc = 0;
    for (int i = s; i < e; i++) acc += cnt[i];
    sums[t] = acc;
    __syncthreads();
    for (int off = 1; off < 1024; off <<= 1) {
        int u = (t >= off) ? sums[t - off] : 0;
        __syncthreads();
        sums[t] += u;
        __syncthreads();
    }
    int excl = sums[t] - acc;
    int run = excl;
    for (int i = s; i < e; i++) { row_ptr[i] = run; run += cnt[i]; }
    if (t == 1023) row_ptr[n] = sums[1023];
}

// ---- CSR fill, XCD-range-partitioned --------------------------------------
__global__ __launch_bounds__(256) void csr_fill_kernel(const int* __restrict__ src,
                                                       const int* __restrict__ dst,
                                                       const int* __restrict__ row_ptr,
                                                       int* __restrict__ fill,
                                                       int* __restrict__ csr_src,
                                                       int E, int N) {
    int g  = blockIdx.x & 7;
    int gb = blockIdx.x >> 3;
    int group_blocks = gridDim.x >> 3;
    int R  = (N + 7) >> 3;
    int lo = g * R;
    int hi = lo + R; if (hi > N) hi = N;

    int tig    = gb * blockDim.x + threadIdx.x;
    int stride = group_blocks * blockDim.x;
    int nq = (E + 3) >> 2;

    for (int q = tig; q < nq; q += stride) {
        int e = q * 4;
        if (e + 3 < E) {
            int4 d = *(const int4*)(dst + e);
            if (d.x >= lo && d.x < hi) {
                int pos = row_ptr[d.x] + atomicAdd(&fill[d.x], 1);
                csr_src[pos] = src[e + 0];
            }
            if (d.y >= lo && d.y < hi) {
                int pos = row_ptr[d.y] + atomicAdd(&fill[d.y], 1);
                csr_src[pos] = src[e + 1];
            }
            if (d.z >= lo && d.z < hi) {
                int pos = row_ptr[d.z] + atomicAdd(&fill[d.z], 1);
                csr_src[pos] = src[e + 2];
            }
            if (d.w >= lo && d.w < hi) {
                int pos = row_ptr[d.w] + atomicAdd(&fill[d.w], 1);
                csr_src[pos] = src[e + 3];
            }
        } else {
            for (; e < E; e++) {
                int d = dst[e];
                if (d >= lo && d < hi) {
                    int pos = row_ptr[d] + atomicAdd(&fill[d], 1);
                    csr_src[pos] = src[e];
                }
            }
        }
    }
}

// ---- GEMM: C = A @ W, A [n x 128] (std or blocked), C channel-blocked -----
// Blocked layout: X_b[p][row][c] for p = channel-block 0..7, c = 0..15.
// Grid = (row tiles of 64) x (2 col-halves of 64). W-half in 32KB LDS.
__global__ __launch_bounds__(256) void gemm_kernel(const float* __restrict__ A,
                                                   const float* __restrict__ W,
                                                   float* __restrict__ C, int n,
                                                   int a_blocked) {
    __shared__ float sW[128 * 64];
    int t = threadIdx.x;
    int col0 = (blockIdx.x & 1) * 64;
    int row0 = (blockIdx.x >> 1) * 64;

    #pragma unroll
    for (int i = 0; i < 8; i++) {
        int fidx = t + 256 * i;
        int k  = fidx >> 4;
        int c4 = fidx & 15;
        *(float4*)(sW + k * 64 + c4 * 4) =
            *(const float4*)(W + (size_t)k * 128 + col0 + c4 * 4);
    }
    __syncthreads();

    int cg = (t & 15) * 4;
    int rg = (t >> 4) * 4;
    int rbase = row0 + rg;

    auto loadA = [&](int rr, int k) -> float4 {
        if (rr >= n) return make_float4(0.f, 0.f, 0.f, 0.f);
        if (a_blocked)
            return *(const float4*)(A + ((size_t)(k >> 4) * n + rr) * 16 + (k & 15));
        return *(const float4*)(A + (size_t)rr * 128 + k);
    };

    float acc[4][4];
    #pragma unroll
    for (int r = 0; r < 4; r++)
        #pragma unroll
        for (int c = 0; c < 4; c++) acc[r][c] = 0.f;

    float4 a_cur[4], a_nxt[4];
    #pragma unroll
    for (int r = 0; r < 4; r++) a_cur[r] = loadA(rbase + r, 0);

    for (int k = 0; k < 128; k += 4) {
        if (k + 4 < 128) {
            #pragma unroll
            for (int r = 0; r < 4; r++) a_nxt[r] = loadA(rbase + r, k + 4);
        }
        #pragma unroll
        for (int kk = 0; kk < 4; kk++) {
            float4 w = *(const float4*)(sW + (size_t)(k + kk) * 64 + cg);
            #pragma unroll
            for (int r = 0; r < 4; r++) {
                float av = (kk == 0) ? a_cur[r].x : (kk == 1) ? a_cur[r].y
                         : (kk == 2) ? a_cur[r].z : a_cur[r].w;
                acc[r][0] = fmaf(av, w.x, acc[r][0]);
                acc[r][1] = fmaf(av, w.y, acc[r][1]);
                acc[r][2] = fmaf(av, w.z, acc[r][2]);
                acc[r][3] = fmaf(av, w.w, acc[r][3]);
            }
        }
        #pragma unroll
        for (int r = 0; r < 4; r++) a_cur[r] = a_nxt[r];
    }

    int cb = col0 + cg;                 // global col of the 4-col group
    float* Cb = C + ((size_t)(cb >> 4) * n) * 16 + (cb & 15);
    #pragma unroll
    for (int r = 0; r < 4; r++) {
        int rr = rbase + r;
        if (rr < n)
            *(float4*)(Cb + (size_t)rr * 16) =
                make_float4(acc[r][0], acc[r][1], acc[r][2], acc[r][3]);
    }
}

// ---- Aggregation, channel-sliced ------------------------------------------
// pass p = blockIdx&7 (-> XCD p under round-robin dispatch): each XCD works
// one 16-channel slice h_b[p] (3.2MB, L2-resident). Wave = 4 nodes x 16 ch.
__global__ __launch_bounds__(256) void agg_kernel(const float* __restrict__ h,
                                                  const int* __restrict__ row_ptr,
                                                  const int* __restrict__ csr_src,
                                                  const float* __restrict__ dinv,
                                                  const float* __restrict__ bias,
                                                  float* __restrict__ out, int n) {
    int p     = blockIdx.x & 7;
    int chunk = blockIdx.x >> 3;
    int wave  = threadIdx.x >> 6;
    int lane  = threadIdx.x & 63;
    int sub   = lane >> 4;
    int ch    = lane & 15;
    int i = chunk * 16 + wave * 4 + sub;

    const float* slice  = h   + (size_t)p * n * 16;
    float*       oslice = out + (size_t)p * n * 16;

    bool valid = (i < n);
    float di  = valid ? dinv[i] : 0.f;
    float acc = valid ? slice[(size_t)i * 16 + ch] * di : 0.f;
    int beg = valid ? row_ptr[i]     : 0;
    int end = valid ? row_ptr[i + 1] : 0;
    int base_lane = lane & 48;

    int e0 = beg;
    while (__any(e0 < end)) {
        int rem = end - e0;                      // subgroup-uniform
        int s_reg = 0; float cf = 0.f;
        if (ch < rem) {
            s_reg = __builtin_nontemporal_load(csr_src + e0 + ch);
            cf = dinv[s_reg];
        }
        int jmax = rem < 16 ? (rem < 0 ? 0 : rem) : 16;
        int j = 0;
        for (; j + 4 <= jmax; j += 4) {
            int   s0 = __shfl(s_reg, base_lane | (j + 0));
            int   s1 = __shfl(s_reg, base_lane | (j + 1));
            int   s2 = __shfl(s_reg, base_lane | (j + 2));
            int   s3 = __shfl(s_reg, base_lane | (j + 3));
            float c0 = __shfl(cf,    base_lane | (j + 0));
            float c1 = __shfl(cf,    base_lane | (j + 1));
            float c2 = __shfl(cf,    base_lane | (j + 2));
            float c3 = __shfl(cf,    base_lane | (j + 3));
            float v0 = slice[(size_t)s0 * 16 + ch];
            float v1 = slice[(size_t)s1 * 16 + ch];
            float v2 = slice[(size_t)s2 * 16 + ch];
            float v3 = slice[(size_t)s3 * 16 + ch];
            acc = fmaf(v0, c0, acc);
            acc = fmaf(v1, c1, acc);
            acc = fmaf(v2, c2, acc);
            acc = fmaf(v3, c3, acc);
        }
        for (; j < jmax; j++) {
            int   sj = __shfl(s_reg, base_lane | j);
            float cj = __shfl(cf,    base_lane | j);
            acc = fmaf(slice[(size_t)sj * 16 + ch], cj, acc);
        }
        e0 += 16;
    }

    if (valid) {
        float b = bias[p * 16 + ch];
        oslice[(size_t)i * 16 + ch] = fmaxf(fmaf(acc, di, b), 0.f);
    }
}

// ---- pool stage 1: partial sums (blocked h) -> atomicAdd ------------------
__global__ __launch_bounds__(128) void pool_partial_kernel(const float* __restrict__ h,
                                                           const int* __restrict__ batch,
                                                           float* __restrict__ sums,
                                                           int n, int S) {
    int g = blockIdx.x / S;
    int s = blockIdx.x % S;
    int c = threadIdx.x;
    const float* hb = h + ((size_t)(c >> 4) * n) * 16 + (c & 15);

    int lo = 0, hi = n;
    while (lo < hi) { int mid = (lo + hi) >> 1; if (batch[mid] < g) lo = mid + 1; else hi = mid; }
    int start = lo;
    lo = start; hi = n;
    while (lo < hi) { int mid = (lo + hi) >> 1; if (batch[mid] < g + 1) lo = mid + 1; else hi = mid; }
    int end = lo;

    int cnt = end - start;
    int per = (cnt + S - 1) / S;
    int rs = start + s * per;
    int re = rs + per; if (re > end) re = end;
    if (rs >= re) return;

    float a0 = 0.f, a1 = 0.f, a2 = 0.f, a3 = 0.f;
    int r = rs;
    for (; r + 4 <= re; r += 4) {
        a0 += hb[(size_t)(r + 0) * 16];
        a1 += hb[(size_t)(r + 1) * 16];
        a2 += hb[(size_t)(r + 2) * 16];
        a3 += hb[(size_t)(r + 3) * 16];
    }
    for (; r < re; r++) a0 += hb[(size_t)r * 16];
    atomicAdd(&sums[g * 128 + c], (a0 + a1) + (a2 + a3));
}

// ---- pool stage 2: mean + FC(128->1), fp64 reduce -------------------------
__global__ __launch_bounds__(128) void pool_fc_final_kernel(const float* __restrict__ sums,
                                                            const int* __restrict__ batch,
                                                            const float* __restrict__ Wfc,
                                                            const float* __restrict__ bfc,
                                                            float* __restrict__ out, int n) {
    int g = blockIdx.x;
    int c = threadIdx.x;

    int lo = 0, hi = n;
    while (lo < hi) { int mid = (lo + hi) >> 1; if (batch[mid] < g) lo = mid + 1; else hi = mid; }
    int start = lo;
    lo = start; hi = n;
    while (lo < hi) { int mid = (lo + hi) >> 1; if (batch[mid] < g + 1) lo = mid + 1; else hi = mid; }
    int cnt = lo - start;

    double mean = (double)sums[g * 128 + c] / (double)(cnt > 0 ? cnt : 1);
    double v = mean * (double)Wfc[c];

    __shared__ double red[128];
    red[c] = v;
    __syncthreads();
    for (int off = 64; off > 0; off >>= 1) {
        if (c < off) red[c] += red[c + off];
        __syncthreads();
    }
    if (c == 0) out[g] = (float)(red[0] + (double)bfc[0]);
}

// ---------------------------------------------------------------------------
extern "C" void kernel_launch(void* const* d_in, const int* in_sizes, int n_in,
                              void* d_out, int out_size, void* d_ws, size_t ws_size,
                              hipStream_t stream) {
    const float* x          = (const float*)d_in[0];
    const int*   edge_index = (const int*)d_in[1];
    const int*   batch      = (const int*)d_in[2];
    const float* W1  = (const float*)d_in[3];
    const float* b1  = (const float*)d_in[4];
    const float* W2  = (const float*)d_in[5];
    const float* b2  = (const float*)d_in[6];
    const float* Wfc = (const float*)d_in[7];
    const float* bfc = (const float*)d_in[8];
    float* out = (float*)d_out;

    const int N = in_sizes[2];       // 50000
    const int E = in_sizes[1] / 2;   // 1600000
    const int G = out_size;          // 128 graphs

    const int* e_src = edge_index;
    const int* e_dst = edge_index + E;

    char* p = (char*)d_ws;
    auto alloc = [&](size_t bytes) {
        void* r = (void*)p;
        p += (bytes + 255) & ~(size_t)255;
        return r;
    };
    float* h0        = (float*)alloc((size_t)N * 128 * 4);
    float* h1        = (float*)alloc((size_t)N * 128 * 4);
    int*   csr_src   = (int*)  alloc((size_t)E * 4);
    int*   row_ptr   = (int*)  alloc((size_t)(N + 1) * 4);
    int*   deg_cnt   = (int*)  alloc((size_t)N * 4);
    int*   fill      = (int*)  alloc((size_t)N * 4);
    float* dinv      = (float*)alloc((size_t)N * 4);
    float* pool_sums = (float*)alloc((size_t)G * 128 * 4);
    (void)ws_size; (void)n_in;

    hipMemsetAsync(deg_cnt,   0, (size_t)N * 4, stream);
    hipMemsetAsync(fill,      0, (size_t)N * 4, stream);
    hipMemsetAsync(pool_sums, 0, (size_t)G * 128 * 4, stream);

    int tb = 256;
    int e4 = (E + 3) / 4;
    count_deg_kernel<<<(e4 + tb - 1) / tb, tb, 0, stream>>>(e_dst, deg_cnt, E);
    dinv_kernel<<<(N + tb - 1) / tb, tb, 0, stream>>>(deg_cnt, dinv, N);
    scan_kernel<<<1, 1024, 0, stream>>>(deg_cnt, row_ptr, N);
    csr_fill_kernel<<<1024, 256, 0, stream>>>(e_src, e_dst, row_ptr, fill, csr_src, E, N);

    int gemm_blocks = 2 * ((N + 63) / 64);
    int agg_blocks  = 8 * ((N + 15) / 16);

    gemm_kernel<<<gemm_blocks, 256, 0, stream>>>(x, W1, h1, N, 0);
    agg_kernel<<<agg_blocks, 256, 0, stream>>>(h1, row_ptr, csr_src, dinv, b1, h0, N);

    for (int l = 0; l < 3; l++) {
        gemm_kernel<<<gemm_blocks, 256, 0, stream>>>(h0, W2, h1, N, 1);
        agg_kernel<<<agg_blocks, 256, 0, stream>>>(h1, row_ptr, csr_src, dinv, b2, h0, N);
    }

    const int S = 8;
    pool_partial_kernel<<<G * S, 128, 0, stream>>>(h0, batch, pool_sums, N, S);
    pool_fc_final_kernel<<<G, 128, 0, stream>>>(pool_sums, batch, Wfc, bfc, out, N);
}

// Round 5
// 994.630 us; speedup vs baseline: 1.1322x; 1.1322x over previous
//
#include <hip/hip_runtime.h>
#include <hip/hip_bf16.h>

// ---------------------------------------------------------------------------
// GCNRegression: 4x (GEMM 128x128 + symmetric-norm aggregation + ReLU),
// then global mean pool (128 graphs) + FC(128->1).
//
// R4 notes:
//  - XCD slicing worked (FETCH 359->64MB) but agg got latency-bound:
//    5 TB/s effective on L2 gathers (ceiling ~34.5). Fixes:
//    * float4-per-lane gathers: 1 KB per wave-load (16 edges), 16x fewer
//      gather instrs; xor-butterfly reduce over 4 edge-slots.
//    * gemm epilogue pre-scales rows by dinv[row] -> no per-edge dinv
//      gather; self term folds into (sum + slice[i]) * d_i + b.
//    * csr_src as uint16 (N<65536): halves csr stream, protects L2 slice.
//    * count_deg partitioned by XCD like csr_fill.
// ---------------------------------------------------------------------------

// ---- degree histogram, XCD-range-partitioned ------------------------------
__global__ __launch_bounds__(256) void count_deg_kernel(const int* __restrict__ dst,
                                                        int* __restrict__ deg, int E, int N) {
    int g  = blockIdx.x & 7;
    int gb = blockIdx.x >> 3;
    int group_blocks = gridDim.x >> 3;
    int R  = (N + 7) >> 3;
    int lo = g * R;
    int hi = lo + R; if (hi > N) hi = N;
    int tig    = gb * blockDim.x + threadIdx.x;
    int stride = group_blocks * blockDim.x;
    int nq = (E + 3) >> 2;
    for (int q = tig; q < nq; q += stride) {
        int e = q * 4;
        if (e + 3 < E) {
            int4 d = *(const int4*)(dst + e);
            if (d.x >= lo && d.x < hi) atomicAdd(&deg[d.x], 1);
            if (d.y >= lo && d.y < hi) atomicAdd(&deg[d.y], 1);
            if (d.z >= lo && d.z < hi) atomicAdd(&deg[d.z], 1);
            if (d.w >= lo && d.w < hi) atomicAdd(&deg[d.w], 1);
        } else {
            for (; e < E; e++) {
                int d = dst[e];
                if (d >= lo && d < hi) atomicAdd(&deg[d], 1);
            }
        }
    }
}

// ---- dinv = 1/sqrt(deg+1) -------------------------------------------------
__global__ void dinv_kernel(const int* __restrict__ deg, float* __restrict__ dinv, int n) {
    int i = blockIdx.x * blockDim.x + threadIdx.x;
    if (i < n) dinv[i] = (float)(1.0 / sqrt((double)(deg[i] + 1)));
}

// ---- single-block exclusive scan -> row_ptr -------------------------------
__global__ void scan_kernel(const int* __restrict__ cnt, int* __restrict__ row_ptr, int n) {
    __shared__ int sums[1024];
    int t = threadIdx.x;
    int per = (n + 1023) >> 10;
    int s = t * per;
    int e = s + per; if (e > n) e = n; if (s > n) s = n;
    int acc = 0;
    for (int i = s; i < e; i++) acc += cnt[i];
    sums[t] = acc;
    __syncthreads();
    for (int off = 1; off < 1024; off <<= 1) {
        int u = (t >= off) ? sums[t - off] : 0;
        __syncthreads();
        sums[t] += u;
        __syncthreads();
    }
    int excl = sums[t] - acc;
    int run = excl;
    for (int i = s; i < e; i++) { row_ptr[i] = run; run += cnt[i]; }
    if (t == 1023) row_ptr[n] = sums[1023];
}

// ---- CSR fill (uint16 src), XCD-range-partitioned -------------------------
__global__ __launch_bounds__(256) void csr_fill_kernel(const int* __restrict__ src,
                                                       const int* __restrict__ dst,
                                                       const int* __restrict__ row_ptr,
                                                       int* __restrict__ fill,
                                                       unsigned short* __restrict__ csr_src,
                                                       int E, int N) {
    int g  = blockIdx.x & 7;
    int gb = blockIdx.x >> 3;
    int group_blocks = gridDim.x >> 3;
    int R  = (N + 7) >> 3;
    int lo = g * R;
    int hi = lo + R; if (hi > N) hi = N;

    int tig    = gb * blockDim.x + threadIdx.x;
    int stride = group_blocks * blockDim.x;
    int nq = (E + 3) >> 2;

    for (int q = tig; q < nq; q += stride) {
        int e = q * 4;
        if (e + 3 < E) {
            int4 d = *(const int4*)(dst + e);
            if (d.x >= lo && d.x < hi) {
                int pos = row_ptr[d.x] + atomicAdd(&fill[d.x], 1);
                csr_src[pos] = (unsigned short)src[e + 0];
            }
            if (d.y >= lo && d.y < hi) {
                int pos = row_ptr[d.y] + atomicAdd(&fill[d.y], 1);
                csr_src[pos] = (unsigned short)src[e + 1];
            }
            if (d.z >= lo && d.z < hi) {
                int pos = row_ptr[d.z] + atomicAdd(&fill[d.z], 1);
                csr_src[pos] = (unsigned short)src[e + 2];
            }
            if (d.w >= lo && d.w < hi) {
                int pos = row_ptr[d.w] + atomicAdd(&fill[d.w], 1);
                csr_src[pos] = (unsigned short)src[e + 3];
            }
        } else {
            for (; e < E; e++) {
                int d = dst[e];
                if (d >= lo && d < hi) {
                    int pos = row_ptr[d] + atomicAdd(&fill[d], 1);
                    csr_src[pos] = (unsigned short)src[e];
                }
            }
        }
    }
}

// ---- GEMM: C = (A @ W) * dinv[row], C channel-blocked [8][n][16] ----------
// A is standard [n x 128] (layer 1) or blocked (layers 2-4).
__global__ __launch_bounds__(256) void gemm_kernel(const float* __restrict__ A,
                                                   const float* __restrict__ W,
                                                   const float* __restrict__ dinv,
                                                   float* __restrict__ C, int n,
                                                   int a_blocked) {
    __shared__ float sW[128 * 64];
    int t = threadIdx.x;
    int col0 = (blockIdx.x & 1) * 64;
    int row0 = (blockIdx.x >> 1) * 64;

    #pragma unroll
    for (int i = 0; i < 8; i++) {
        int fidx = t + 256 * i;
        int k  = fidx >> 4;
        int c4 = fidx & 15;
        *(float4*)(sW + k * 64 + c4 * 4) =
            *(const float4*)(W + (size_t)k * 128 + col0 + c4 * 4);
    }
    __syncthreads();

    int cg = (t & 15) * 4;
    int rg = (t >> 4) * 4;
    int rbase = row0 + rg;

    auto loadA = [&](int rr, int k) -> float4 {
        if (rr >= n) return make_float4(0.f, 0.f, 0.f, 0.f);
        if (a_blocked)
            return *(const float4*)(A + ((size_t)(k >> 4) * n + rr) * 16 + (k & 15));
        return *(const float4*)(A + (size_t)rr * 128 + k);
    };

    float acc[4][4];
    #pragma unroll
    for (int r = 0; r < 4; r++)
        #pragma unroll
        for (int c = 0; c < 4; c++) acc[r][c] = 0.f;

    float4 a_cur[4], a_nxt[4];
    #pragma unroll
    for (int r = 0; r < 4; r++) a_cur[r] = loadA(rbase + r, 0);

    for (int k = 0; k < 128; k += 4) {
        if (k + 4 < 128) {
            #pragma unroll
            for (int r = 0; r < 4; r++) a_nxt[r] = loadA(rbase + r, k + 4);
        }
        #pragma unroll
        for (int kk = 0; kk < 4; kk++) {
            float4 w = *(const float4*)(sW + (size_t)(k + kk) * 64 + cg);
            #pragma unroll
            for (int r = 0; r < 4; r++) {
                float av = (kk == 0) ? a_cur[r].x : (kk == 1) ? a_cur[r].y
                         : (kk == 2) ? a_cur[r].z : a_cur[r].w;
                acc[r][0] = fmaf(av, w.x, acc[r][0]);
                acc[r][1] = fmaf(av, w.y, acc[r][1]);
                acc[r][2] = fmaf(av, w.z, acc[r][2]);
                acc[r][3] = fmaf(av, w.w, acc[r][3]);
            }
        }
        #pragma unroll
        for (int r = 0; r < 4; r++) a_cur[r] = a_nxt[r];
    }

    int cb = col0 + cg;
    float* Cb = C + ((size_t)(cb >> 4) * n) * 16 + (cb & 15);
    #pragma unroll
    for (int r = 0; r < 4; r++) {
        int rr = rbase + r;
        if (rr < n) {
            float dsc = dinv[rr];
            *(float4*)(Cb + (size_t)rr * 16) =
                make_float4(acc[r][0] * dsc, acc[r][1] * dsc,
                            acc[r][2] * dsc, acc[r][3] * dsc);
        }
    }
}

// ---- Aggregation, channel-sliced, float4 gathers --------------------------
// h holds pre-scaled rows (h*dinv[row]) blocked [8][n][16].
// pass p = blockIdx&7 -> XCD p works its private 3.2MB slice (L2-resident).
// Wave = 4 nodes; per node: 4 edge-slots x 4 channel-quads (float4/lane).
// out[i] = relu( (sum_edges slice[src] + slice[i]) * dinv[i] + b )
__global__ __launch_bounds__(256) void agg_kernel(const float* __restrict__ h,
                                                  const int* __restrict__ row_ptr,
                                                  const unsigned short* __restrict__ csr_src,
                                                  const float* __restrict__ dinv,
                                                  const float* __restrict__ bias,
                                                  float* __restrict__ out, int n) {
    int p     = blockIdx.x & 7;
    int chunk = blockIdx.x >> 3;
    int wave  = threadIdx.x >> 6;
    int lane  = threadIdx.x & 63;
    int sub   = lane >> 4;          // node within wave
    int es    = (lane >> 2) & 3;    // edge slot
    int q     = lane & 3;           // channel quad
    int i = chunk * 16 + wave * 4 + sub;
    bool valid = (i < n);
    int iv = valid ? i : 0;

    const float* slice  = h   + (size_t)p * n * 16;
    float*       oslice = out + (size_t)p * n * 16;

    int beg = row_ptr[iv];
    int end = valid ? row_ptr[iv + 1] : beg;

    float4 acc = make_float4(0.f, 0.f, 0.f, 0.f);
    int qoff = q << 2;

    // unroll x2: 8 edges per node in flight (2 independent gather chains)
    int e = beg + es;
    while (__any(e < end)) {
        bool a0 = (e < end);
        bool a1 = (e + 4 < end);
        int  s0 = a0 ? (int)__builtin_nontemporal_load(csr_src + e)     : 0;
        int  s1 = a1 ? (int)__builtin_nontemporal_load(csr_src + e + 4) : 0;
        float w0 = a0 ? 1.f : 0.f;
        float w1 = a1 ? 1.f : 0.f;
        float4 v0 = *(const float4*)(slice + (s0 << 4) + qoff);
        float4 v1 = *(const float4*)(slice + (s1 << 4) + qoff);
        acc.x = fmaf(v0.x, w0, acc.x);
        acc.y = fmaf(v0.y, w0, acc.y);
        acc.z = fmaf(v0.z, w0, acc.z);
        acc.w = fmaf(v0.w, w0, acc.w);
        acc.x = fmaf(v1.x, w1, acc.x);
        acc.y = fmaf(v1.y, w1, acc.y);
        acc.z = fmaf(v1.z, w1, acc.z);
        acc.w = fmaf(v1.w, w1, acc.w);
        e += 8;
    }

    // reduce over the 4 edge-slots (xor masks 4, 8 stay within the subgroup)
    acc.x += __shfl_xor(acc.x, 4);
    acc.y += __shfl_xor(acc.y, 4);
    acc.z += __shfl_xor(acc.z, 4);
    acc.w += __shfl_xor(acc.w, 4);
    acc.x += __shfl_xor(acc.x, 8);
    acc.y += __shfl_xor(acc.y, 8);
    acc.z += __shfl_xor(acc.z, 8);
    acc.w += __shfl_xor(acc.w, 8);

    float di = dinv[iv];
    float4 self = *(const float4*)(slice + (iv << 4) + qoff);
    float4 b4   = *(const float4*)(bias + p * 16 + qoff);
    float4 o;
    o.x = fmaxf(fmaf(acc.x + self.x, di, b4.x), 0.f);
    o.y = fmaxf(fmaf(acc.y + self.y, di, b4.y), 0.f);
    o.z = fmaxf(fmaf(acc.z + self.z, di, b4.z), 0.f);
    o.w = fmaxf(fmaf(acc.w + self.w, di, b4.w), 0.f);

    if (valid && es == 0)
        *(float4*)(oslice + (i << 4) + qoff) = o;
}

// ---- pool stage 1: partial sums (blocked h) -> atomicAdd ------------------
__global__ __launch_bounds__(128) void pool_partial_kernel(const float* __restrict__ h,
                                                           const int* __restrict__ batch,
                                                           float* __restrict__ sums,
                                                           int n, int S) {
    int g = blockIdx.x / S;
    int s = blockIdx.x % S;
    int c = threadIdx.x;
    const float* hb = h + ((size_t)(c >> 4) * n) * 16 + (c & 15);

    int lo = 0, hi = n;
    while (lo < hi) { int mid = (lo + hi) >> 1; if (batch[mid] < g) lo = mid + 1; else hi = mid; }
    int start = lo;
    lo = start; hi = n;
    while (lo < hi) { int mid = (lo + hi) >> 1; if (batch[mid] < g + 1) lo = mid + 1; else hi = mid; }
    int end = lo;

    int cnt = end - start;
    int per = (cnt + S - 1) / S;
    int rs = start + s * per;
    int re = rs + per; if (re > end) re = end;
    if (rs >= re) return;

    float a0 = 0.f, a1 = 0.f, a2 = 0.f, a3 = 0.f;
    int r = rs;
    for (; r + 4 <= re; r += 4) {
        a0 += hb[(size_t)(r + 0) * 16];
        a1 += hb[(size_t)(r + 1) * 16];
        a2 += hb[(size_t)(r + 2) * 16];
        a3 += hb[(size_t)(r + 3) * 16];
    }
    for (; r < re; r++) a0 += hb[(size_t)r * 16];
    atomicAdd(&sums[g * 128 + c], (a0 + a1) + (a2 + a3));
}

// ---- pool stage 2: mean + FC(128->1), fp64 reduce -------------------------
__global__ __launch_bounds__(128) void pool_fc_final_kernel(const float* __restrict__ sums,
                                                            const int* __restrict__ batch,
                                                            const float* __restrict__ Wfc,
                                                            const float* __restrict__ bfc,
                                                            float* __restrict__ out, int n) {
    int g = blockIdx.x;
    int c = threadIdx.x;

    int lo = 0, hi = n;
    while (lo < hi) { int mid = (lo + hi) >> 1; if (batch[mid] < g) lo = mid + 1; else hi = mid; }
    int start = lo;
    lo = start; hi = n;
    while (lo < hi) { int mid = (lo + hi) >> 1; if (batch[mid] < g + 1) lo = mid + 1; else hi = mid; }
    int cnt = lo - start;

    double mean = (double)sums[g * 128 + c] / (double)(cnt > 0 ? cnt : 1);
    double v = mean * (double)Wfc[c];

    __shared__ double red[128];
    red[c] = v;
    __syncthreads();
    for (int off = 64; off > 0; off >>= 1) {
        if (c < off) red[c] += red[c + off];
        __syncthreads();
    }
    if (c == 0) out[g] = (float)(red[0] + (double)bfc[0]);
}

// ---------------------------------------------------------------------------
extern "C" void kernel_launch(void* const* d_in, const int* in_sizes, int n_in,
                              void* d_out, int out_size, void* d_ws, size_t ws_size,
                              hipStream_t stream) {
    const float* x          = (const float*)d_in[0];
    const int*   edge_index = (const int*)d_in[1];
    const int*   batch      = (const int*)d_in[2];
    const float* W1  = (const float*)d_in[3];
    const float* b1  = (const float*)d_in[4];
    const float* W2  = (const float*)d_in[5];
    const float* b2  = (const float*)d_in[6];
    const float* Wfc = (const float*)d_in[7];
    const float* bfc = (const float*)d_in[8];
    float* out = (float*)d_out;

    const int N = in_sizes[2];       // 50000
    const int E = in_sizes[1] / 2;   // 1600000
    const int G = out_size;          // 128 graphs

    const int* e_src = edge_index;
    const int* e_dst = edge_index + E;

    char* p = (char*)d_ws;
    auto alloc = [&](size_t bytes) {
        void* r = (void*)p;
        p += (bytes + 255) & ~(size_t)255;
        return r;
    };
    float*          h0        = (float*)alloc((size_t)N * 128 * 4);
    float*          h1        = (float*)alloc((size_t)N * 128 * 4);
    unsigned short* csr_src   = (unsigned short*)alloc((size_t)E * 2);
    int*            row_ptr   = (int*)  alloc((size_t)(N + 1) * 4);
    int*            deg_cnt   = (int*)  alloc((size_t)N * 4);
    int*            fill      = (int*)  alloc((size_t)N * 4);
    float*          dinv      = (float*)alloc((size_t)N * 4);
    float*          pool_sums = (float*)alloc((size_t)G * 128 * 4);
    (void)ws_size; (void)n_in;

    hipMemsetAsync(deg_cnt,   0, (size_t)N * 4, stream);
    hipMemsetAsync(fill,      0, (size_t)N * 4, stream);
    hipMemsetAsync(pool_sums, 0, (size_t)G * 128 * 4, stream);

    int tb = 256;
    count_deg_kernel<<<1024, tb, 0, stream>>>(e_dst, deg_cnt, E, N);
    dinv_kernel<<<(N + tb - 1) / tb, tb, 0, stream>>>(deg_cnt, dinv, N);
    scan_kernel<<<1, 1024, 0, stream>>>(deg_cnt, row_ptr, N);
    csr_fill_kernel<<<1024, tb, 0, stream>>>(e_src, e_dst, row_ptr, fill, csr_src, E, N);

    int gemm_blocks = 2 * ((N + 63) / 64);
    int agg_blocks  = 8 * ((N + 15) / 16);

    gemm_kernel<<<gemm_blocks, 256, 0, stream>>>(x, W1, dinv, h1, N, 0);
    agg_kernel<<<agg_blocks, 256, 0, stream>>>(h1, row_ptr, csr_src, dinv, b1, h0, N);

    for (int l = 0; l < 3; l++) {
        gemm_kernel<<<gemm_blocks, 256, 0, stream>>>(h0, W2, dinv, h1, N, 1);
        agg_kernel<<<agg_blocks, 256, 0, stream>>>(h1, row_ptr, csr_src, dinv, b2, h0, N);
    }

    const int S = 8;
    pool_partial_kernel<<<G * S, 128, 0, stream>>>(h0, batch, pool_sums, N, S);
    pool_fc_final_kernel<<<G, 128, 0, stream>>>(pool_sums, batch, Wfc, bfc, out, N);
}

// Round 7
// 867.135 us; speedup vs baseline: 1.2986x; 1.1470x over previous
//
#include <hip/hip_runtime.h>
#include <hip/hip_bf16.h>

// ---------------------------------------------------------------------------
// GCNRegression: 4x (GEMM 128x128 + symmetric-norm aggregation + ReLU),
// then global mean pool (128 graphs) + FC(128->1).
//
// R6 post-mortem: layer-1 GEMM read wrong A data (bump was 128 = next ROW
// instead of 16 = next k-chunk for the row-major layout). Fixed. Pool made
// deterministic (fp64 partial slots, no atomics) for absmax margin.
// ---------------------------------------------------------------------------

// ---- degree histogram (single pass, int4 reads) ---------------------------
__global__ void count_deg_kernel(const int* __restrict__ dst, int* __restrict__ deg, int E) {
    int i = blockIdx.x * blockDim.x + threadIdx.x;
    int e = i * 4;
    if (e + 3 < E) {
        int4 d = *(const int4*)(dst + e);
        atomicAdd(&deg[d.x], 1);
        atomicAdd(&deg[d.y], 1);
        atomicAdd(&deg[d.z], 1);
        atomicAdd(&deg[d.w], 1);
    } else {
        for (; e < E; e++) atomicAdd(&deg[dst[e]], 1);
    }
}

// ---- dinv = 1/sqrt(deg+1) -------------------------------------------------
__global__ void dinv_kernel(const int* __restrict__ deg, float* __restrict__ dinv, int n) {
    int i = blockIdx.x * blockDim.x + threadIdx.x;
    if (i < n) dinv[i] = (float)(1.0 / sqrt((double)(deg[i] + 1)));
}

// ---- single-block exclusive scan -> row_ptr -------------------------------
__global__ void scan_kernel(const int* __restrict__ cnt, int* __restrict__ row_ptr, int n) {
    __shared__ int sums[1024];
    int t = threadIdx.x;
    int per = (n + 1023) >> 10;
    int s = t * per;
    int e = s + per; if (e > n) e = n; if (s > n) s = n;
    int acc = 0;
    for (int i = s; i < e; i++) acc += cnt[i];
    sums[t] = acc;
    __syncthreads();
    for (int off = 1; off < 1024; off <<= 1) {
        int u = (t >= off) ? sums[t - off] : 0;
        __syncthreads();
        sums[t] += u;
        __syncthreads();
    }
    int excl = sums[t] - acc;
    int run = excl;
    for (int i = s; i < e; i++) { row_ptr[i] = run; run += cnt[i]; }
    if (t == 1023) row_ptr[n] = sums[1023];
}

// ---- CSR fill (uint16 src), XCD-range-partitioned -------------------------
__global__ __launch_bounds__(256) void csr_fill_kernel(const int* __restrict__ src,
                                                       const int* __restrict__ dst,
                                                       const int* __restrict__ row_ptr,
                                                       int* __restrict__ fill,
                                                       unsigned short* __restrict__ csr_src,
                                                       int E, int N) {
    int g  = blockIdx.x & 7;
    int gb = blockIdx.x >> 3;
    int group_blocks = gridDim.x >> 3;
    int R  = (N + 7) >> 3;
    int lo = g * R;
    int hi = lo + R; if (hi > N) hi = N;

    int tig    = gb * blockDim.x + threadIdx.x;
    int stride = group_blocks * blockDim.x;
    int nq = (E + 3) >> 2;

    for (int q = tig; q < nq; q += stride) {
        int e = q * 4;
        if (e + 3 < E) {
            int4 d = *(const int4*)(dst + e);
            if (d.x >= lo && d.x < hi) {
                int pos = row_ptr[d.x] + atomicAdd(&fill[d.x], 1);
                csr_src[pos] = (unsigned short)src[e + 0];
            }
            if (d.y >= lo && d.y < hi) {
                int pos = row_ptr[d.y] + atomicAdd(&fill[d.y], 1);
                csr_src[pos] = (unsigned short)src[e + 1];
            }
            if (d.z >= lo && d.z < hi) {
                int pos = row_ptr[d.z] + atomicAdd(&fill[d.z], 1);
                csr_src[pos] = (unsigned short)src[e + 2];
            }
            if (d.w >= lo && d.w < hi) {
                int pos = row_ptr[d.w] + atomicAdd(&fill[d.w], 1);
                csr_src[pos] = (unsigned short)src[e + 3];
            }
        } else {
            for (; e < E; e++) {
                int d = dst[e];
                if (d >= lo && d < hi) {
                    int pos = row_ptr[d] + atomicAdd(&fill[d], 1);
                    csr_src[pos] = (unsigned short)src[e];
                }
            }
        }
    }
}

// ---- GEMM: C = (A @ W) * dinv[row], C channel-blocked [8][n][16] ----------
// 128 rows x 32 cols per 256-thread block; W quarter (16KB) in LDS.
// Per thread 4 rows x 4 cols; A pointer-incremented per 16-k block:
//   non-blocked (row-major [n][128]): stage s at A+rr*128+16s  -> bump 16
//   blocked     ([8][n][16]):         stage s at A+(s*n+rr)*16 -> bump n*16
__global__ __launch_bounds__(256) void gemm_kernel(const float* __restrict__ A,
                                                   const float* __restrict__ W,
                                                   const float* __restrict__ dinv,
                                                   float* __restrict__ C, int n,
                                                   int a_blocked) {
    __shared__ float sW[128 * 32];
    int t = threadIdx.x;
    int col0 = (blockIdx.x & 3) * 32;
    int row0 = (blockIdx.x >> 2) * 128;

    #pragma unroll
    for (int i = 0; i < 4; i++) {
        int fidx = t + 256 * i;            // 1024 float4
        int k  = fidx >> 3;
        int c4 = fidx & 7;
        *(float4*)(sW + k * 32 + c4 * 4) =
            *(const float4*)(W + (size_t)k * 128 + col0 + c4 * 4);
    }
    __syncthreads();

    int cg = (t & 7) * 4;          // 4 cols within the 32-col tile
    int rg = (t >> 3) * 4;         // 4 rows
    int rbase = row0 + rg;

    const float* ap[4];
    #pragma unroll
    for (int r = 0; r < 4; r++) {
        int rr = rbase + r; if (rr > n - 1) rr = n - 1;   // clamp (store guarded)
        ap[r] = a_blocked ? (A + (size_t)rr * 16) : (A + (size_t)rr * 128);
    }
    size_t bump = a_blocked ? (size_t)n * 16 : (size_t)16;   // R6 bug: was 128

    float acc[4][4];
    #pragma unroll
    for (int r = 0; r < 4; r++)
        #pragma unroll
        for (int c = 0; c < 4; c++) acc[r][c] = 0.f;

    // bufA holds k = kb*16+0..7, bufB holds k = kb*16+8..15
    float4 bufA[4][2], bufB[4][2];
    #pragma unroll
    for (int r = 0; r < 4; r++) {
        bufA[r][0] = *(const float4*)(ap[r] + 0);
        bufA[r][1] = *(const float4*)(ap[r] + 4);
        bufB[r][0] = *(const float4*)(ap[r] + 8);
        bufB[r][1] = *(const float4*)(ap[r] + 12);
        ap[r] += bump;
    }

    #pragma unroll 1
    for (int kb = 0; kb < 8; kb++) {
        const float* wrow = sW + kb * 16 * 32 + cg;
        #pragma unroll
        for (int kk = 0; kk < 8; kk++) {
            float4 w = *(const float4*)(wrow + kk * 32);
            #pragma unroll
            for (int r = 0; r < 4; r++) {
                float4 aq = bufA[r][kk >> 2];
                float av = ((kk & 3) == 0) ? aq.x : ((kk & 3) == 1) ? aq.y
                         : ((kk & 3) == 2) ? aq.z : aq.w;
                acc[r][0] = fmaf(av, w.x, acc[r][0]);
                acc[r][1] = fmaf(av, w.y, acc[r][1]);
                acc[r][2] = fmaf(av, w.z, acc[r][2]);
                acc[r][3] = fmaf(av, w.w, acc[r][3]);
            }
        }
        if (kb < 7) {   // reload bufA for kb+1; used after bufB compute (128 FMA gap)
            #pragma unroll
            for (int r = 0; r < 4; r++) {
                bufA[r][0] = *(const float4*)(ap[r] + 0);
                bufA[r][1] = *(const float4*)(ap[r] + 4);
            }
        }
        #pragma unroll
        for (int kk = 0; kk < 8; kk++) {
            float4 w = *(const float4*)(wrow + (8 + kk) * 32);
            #pragma unroll
            for (int r = 0; r < 4; r++) {
                float4 aq = bufB[r][kk >> 2];
                float av = ((kk & 3) == 0) ? aq.x : ((kk & 3) == 1) ? aq.y
                         : ((kk & 3) == 2) ? aq.z : aq.w;
                acc[r][0] = fmaf(av, w.x, acc[r][0]);
                acc[r][1] = fmaf(av, w.y, acc[r][1]);
                acc[r][2] = fmaf(av, w.z, acc[r][2]);
                acc[r][3] = fmaf(av, w.w, acc[r][3]);
            }
        }
        if (kb < 7) {
            #pragma unroll
            for (int r = 0; r < 4; r++) {
                bufB[r][0] = *(const float4*)(ap[r] + 8);
                bufB[r][1] = *(const float4*)(ap[r] + 12);
                ap[r] += bump;
            }
        }
    }

    int cb = col0 + cg;
    float* Cb = C + (size_t)(cb >> 4) * n * 16 + (cb & 15);
    #pragma unroll
    for (int r = 0; r < 4; r++) {
        int rr = rbase + r;
        if (rr < n) {
            float dsc = dinv[rr];
            *(float4*)(Cb + (size_t)rr * 16) =
                make_float4(acc[r][0] * dsc, acc[r][1] * dsc,
                            acc[r][2] * dsc, acc[r][3] * dsc);
        }
    }
}

// ---- Aggregation, channel-sliced, 4 gather chains + csr prefetch ----------
// h holds pre-scaled rows (h*dinv[row]) blocked [8][n][16].
// out[i] = relu( (sum_edges slice[src] + slice[i]) * dinv[i] + b )
__global__ __launch_bounds__(256) void agg_kernel(const float* __restrict__ h,
                                                  const int* __restrict__ row_ptr,
                                                  const unsigned short* __restrict__ csr_src,
                                                  const float* __restrict__ dinv,
                                                  const float* __restrict__ bias,
                                                  float* __restrict__ out, int n) {
    int p     = blockIdx.x & 7;
    int chunk = blockIdx.x >> 3;
    int wave  = threadIdx.x >> 6;
    int lane  = threadIdx.x & 63;
    int sub   = lane >> 4;          // node within wave
    int es    = (lane >> 2) & 3;    // edge slot
    int q     = lane & 3;           // channel quad
    int i = chunk * 16 + wave * 4 + sub;
    bool valid = (i < n);
    int iv = valid ? i : 0;

    const float* slice  = h   + (size_t)p * n * 16;
    float*       oslice = out + (size_t)p * n * 16;

    int beg = row_ptr[iv];
    int end = valid ? row_ptr[iv + 1] : beg;

    float4 acc = make_float4(0.f, 0.f, 0.f, 0.f);
    int qoff = q << 2;

    int e = beg + es;
    int s0 = (e      < end) ? (int)__builtin_nontemporal_load(csr_src + e)      : -1;
    int s1 = (e + 4  < end) ? (int)__builtin_nontemporal_load(csr_src + e + 4)  : -1;
    int s2 = (e + 8  < end) ? (int)__builtin_nontemporal_load(csr_src + e + 8)  : -1;
    int s3 = (e + 12 < end) ? (int)__builtin_nontemporal_load(csr_src + e + 12) : -1;

    while (__any(e < end)) {
        int en = e + 16;
        int t0 = (en      < end) ? (int)__builtin_nontemporal_load(csr_src + en)      : -1;
        int t1 = (en + 4  < end) ? (int)__builtin_nontemporal_load(csr_src + en + 4)  : -1;
        int t2 = (en + 8  < end) ? (int)__builtin_nontemporal_load(csr_src + en + 8)  : -1;
        int t3 = (en + 12 < end) ? (int)__builtin_nontemporal_load(csr_src + en + 12) : -1;

        float w0 = (s0 >= 0) ? 1.f : 0.f; int g0 = (s0 >= 0) ? s0 : 0;
        float w1 = (s1 >= 0) ? 1.f : 0.f; int g1 = (s1 >= 0) ? s1 : 0;
        float w2 = (s2 >= 0) ? 1.f : 0.f; int g2 = (s2 >= 0) ? s2 : 0;
        float w3 = (s3 >= 0) ? 1.f : 0.f; int g3 = (s3 >= 0) ? s3 : 0;
        float4 v0 = *(const float4*)(slice + (g0 << 4) + qoff);
        float4 v1 = *(const float4*)(slice + (g1 << 4) + qoff);
        float4 v2 = *(const float4*)(slice + (g2 << 4) + qoff);
        float4 v3 = *(const float4*)(slice + (g3 << 4) + qoff);
        acc.x = fmaf(v0.x, w0, acc.x); acc.y = fmaf(v0.y, w0, acc.y);
        acc.z = fmaf(v0.z, w0, acc.z); acc.w = fmaf(v0.w, w0, acc.w);
        acc.x = fmaf(v1.x, w1, acc.x); acc.y = fmaf(v1.y, w1, acc.y);
        acc.z = fmaf(v1.z, w1, acc.z); acc.w = fmaf(v1.w, w1, acc.w);
        acc.x = fmaf(v2.x, w2, acc.x); acc.y = fmaf(v2.y, w2, acc.y);
        acc.z = fmaf(v2.z, w2, acc.z); acc.w = fmaf(v2.w, w2, acc.w);
        acc.x = fmaf(v3.x, w3, acc.x); acc.y = fmaf(v3.y, w3, acc.y);
        acc.z = fmaf(v3.z, w3, acc.z); acc.w = fmaf(v3.w, w3, acc.w);

        e = en; s0 = t0; s1 = t1; s2 = t2; s3 = t3;
    }

    acc.x += __shfl_xor(acc.x, 4);
    acc.y += __shfl_xor(acc.y, 4);
    acc.z += __shfl_xor(acc.z, 4);
    acc.w += __shfl_xor(acc.w, 4);
    acc.x += __shfl_xor(acc.x, 8);
    acc.y += __shfl_xor(acc.y, 8);
    acc.z += __shfl_xor(acc.z, 8);
    acc.w += __shfl_xor(acc.w, 8);

    float di = dinv[iv];
    float4 self = *(const float4*)(slice + (iv << 4) + qoff);
    float4 b4   = *(const float4*)(bias + p * 16 + qoff);
    float4 o;
    o.x = fmaxf(fmaf(acc.x + self.x, di, b4.x), 0.f);
    o.y = fmaxf(fmaf(acc.y + self.y, di, b4.y), 0.f);
    o.z = fmaxf(fmaf(acc.z + self.z, di, b4.z), 0.f);
    o.w = fmaxf(fmaf(acc.w + self.w, di, b4.w), 0.f);

    if (valid && es == 0)
        *(float4*)(oslice + (i << 4) + qoff) = o;
}

// ---- pool stage 1: deterministic fp64 partials, one slot per (g,s) --------
// partials[(g*S+s)*128 + c]; every slot written (0 if empty range).
__global__ __launch_bounds__(128) void pool_partial_kernel(const float* __restrict__ h,
                                                           const int* __restrict__ batch,
                                                           double* __restrict__ partials,
                                                           int n, int S) {
    int g = blockIdx.x / S;
    int s = blockIdx.x % S;
    int c = threadIdx.x;
    const float* hb = h + ((size_t)(c >> 4) * n) * 16 + (c & 15);

    int lo = 0, hi = n;
    while (lo < hi) { int mid = (lo + hi) >> 1; if (batch[mid] < g) lo = mid + 1; else hi = mid; }
    int start = lo;
    lo = start; hi = n;
    while (lo < hi) { int mid = (lo + hi) >> 1; if (batch[mid] < g + 1) lo = mid + 1; else hi = mid; }
    int end = lo;

    int cnt = end - start;
    int per = (cnt + S - 1) / S;
    int rs = start + s * per;
    int re = rs + per; if (re > end) re = end;

    double a0 = 0.0, a1 = 0.0, a2 = 0.0, a3 = 0.0;
    int r = rs;
    for (; r + 4 <= re; r += 4) {
        a0 += (double)hb[(size_t)(r + 0) * 16];
        a1 += (double)hb[(size_t)(r + 1) * 16];
        a2 += (double)hb[(size_t)(r + 2) * 16];
        a3 += (double)hb[(size_t)(r + 3) * 16];
    }
    for (; r < re; r++) a0 += (double)hb[(size_t)r * 16];
    partials[(size_t)(g * S + s) * 128 + c] = (a0 + a1) + (a2 + a3);
}

// ---- pool stage 2: reduce S partials, mean + FC(128->1), fp64 -------------
__global__ __launch_bounds__(128) void pool_fc_final_kernel(const double* __restrict__ partials,
                                                            const int* __restrict__ batch,
                                                            const float* __restrict__ Wfc,
                                                            const float* __restrict__ bfc,
                                                            float* __restrict__ out,
                                                            int n, int S) {
    int g = blockIdx.x;
    int c = threadIdx.x;

    int lo = 0, hi = n;
    while (lo < hi) { int mid = (lo + hi) >> 1; if (batch[mid] < g) lo = mid + 1; else hi = mid; }
    int start = lo;
    lo = start; hi = n;
    while (lo < hi) { int mid = (lo + hi) >> 1; if (batch[mid] < g + 1) lo = mid + 1; else hi = mid; }
    int cnt = lo - start;

    double sum = 0.0;
    for (int s = 0; s < S; s++) sum += partials[(size_t)(g * S + s) * 128 + c];
    double mean = sum / (double)(cnt > 0 ? cnt : 1);
    double v = mean * (double)Wfc[c];

    __shared__ double red[128];
    red[c] = v;
    __syncthreads();
    for (int off = 64; off > 0; off >>= 1) {
        if (c < off) red[c] += red[c + off];
        __syncthreads();
    }
    if (c == 0) out[g] = (float)(red[0] + (double)bfc[0]);
}

// ---------------------------------------------------------------------------
extern "C" void kernel_launch(void* const* d_in, const int* in_sizes, int n_in,
                              void* d_out, int out_size, void* d_ws, size_t ws_size,
                              hipStream_t stream) {
    const float* x          = (const float*)d_in[0];
    const int*   edge_index = (const int*)d_in[1];
    const int*   batch      = (const int*)d_in[2];
    const float* W1  = (const float*)d_in[3];
    const float* b1  = (const float*)d_in[4];
    const float* W2  = (const float*)d_in[5];
    const float* b2  = (const float*)d_in[6];
    const float* Wfc = (const float*)d_in[7];
    const float* bfc = (const float*)d_in[8];
    float* out = (float*)d_out;

    const int N = in_sizes[2];       // 50000
    const int E = in_sizes[1] / 2;   // 1600000
    const int G = out_size;          // 128 graphs

    const int* e_src = edge_index;
    const int* e_dst = edge_index + E;

    char* p = (char*)d_ws;
    auto alloc = [&](size_t bytes) {
        void* r = (void*)p;
        p += (bytes + 255) & ~(size_t)255;
        return r;
    };
    const int S = 8;
    float*          h0        = (float*)alloc((size_t)N * 128 * 4);
    float*          h1        = (float*)alloc((size_t)N * 128 * 4);
    unsigned short* csr_src   = (unsigned short*)alloc((size_t)E * 2);
    int*            row_ptr   = (int*)  alloc((size_t)(N + 1) * 4);
    int*            deg_cnt   = (int*)  alloc((size_t)N * 4);
    int*            fill      = (int*)  alloc((size_t)N * 4);
    float*          dinv      = (float*)alloc((size_t)N * 4);
    double*         partials  = (double*)alloc((size_t)G * S * 128 * 8);
    (void)ws_size; (void)n_in;

    hipMemsetAsync(deg_cnt, 0, (size_t)N * 4, stream);
    hipMemsetAsync(fill,    0, (size_t)N * 4, stream);

    int tb = 256;
    int e4 = (E + 3) / 4;
    count_deg_kernel<<<(e4 + tb - 1) / tb, tb, 0, stream>>>(e_dst, deg_cnt, E);
    dinv_kernel<<<(N + tb - 1) / tb, tb, 0, stream>>>(deg_cnt, dinv, N);
    scan_kernel<<<1, 1024, 0, stream>>>(deg_cnt, row_ptr, N);
    csr_fill_kernel<<<1024, tb, 0, stream>>>(e_src, e_dst, row_ptr, fill, csr_src, E, N);

    int gemm_blocks = 4 * ((N + 127) / 128);
    int agg_blocks  = 8 * ((N + 15) / 16);

    gemm_kernel<<<gemm_blocks, 256, 0, stream>>>(x, W1, dinv, h1, N, 0);
    agg_kernel<<<agg_blocks, 256, 0, stream>>>(h1, row_ptr, csr_src, dinv, b1, h0, N);

    for (int l = 0; l < 3; l++) {
        gemm_kernel<<<gemm_blocks, 256, 0, stream>>>(h0, W2, dinv, h1, N, 1);
        agg_kernel<<<agg_blocks, 256, 0, stream>>>(h1, row_ptr, csr_src, dinv, b2, h0, N);
    }

    pool_partial_kernel<<<G * S, 128, 0, stream>>>(h0, batch, partials, N, S);
    pool_fc_final_kernel<<<G, 128, 0, stream>>>(partials, batch, Wfc, bfc, out, N, S);
}